// Round 9
// baseline (2355.624 us; speedup 1.0000x reference)
//
#include <hip/hip_runtime.h>
#include <hip/hip_fp16.h>
#include <cstddef>
#include <cstdint>

#define NB 64
#define TT 1024
#define DD 512
#define HH 512

typedef _Float16 h2_t __attribute__((ext_vector_type(2)));
typedef __attribute__((ext_vector_type(8))) short bf16x8;
typedef __attribute__((ext_vector_type(4))) float f32x4;
typedef __attribute__((ext_vector_type(8))) unsigned short ushort8;

__device__ __forceinline__ float dot2f(uint32_t a, uint32_t b, float c) {
#if __has_builtin(__builtin_amdgcn_fdot2)
    return __builtin_amdgcn_fdot2(__builtin_bit_cast(h2_t, a),
                                  __builtin_bit_cast(h2_t, b), c, false);
#else
    __half2 av = __builtin_bit_cast(__half2, a);
    __half2 bv = __builtin_bit_cast(__half2, b);
    float2 af = __half22float2(av), bf = __half22float2(bv);
    return fmaf(af.x, bf.x, fmaf(af.y, bf.y, c));
#endif
}

// fast tanh: |err| ~1e-7 (validated r5: absmax unchanged)
__device__ __forceinline__ float fast_tanh(float z) {
    z = fmaxf(-15.f, fminf(15.f, z));
    float u = __builtin_amdgcn_exp2f(-2.885390082f * z);
    return (1.f - u) * __builtin_amdgcn_rcpf(1.f + u);
}

// fp32 -> bf16 bits, round-to-nearest-even
__device__ __forceinline__ unsigned short f2bf(float f) {
    uint32_t u = __builtin_bit_cast(uint32_t, f);
    u += 0x7FFFu + ((u >> 16) & 1u);
    return (unsigned short)(u >> 16);
}

// ---------------------------------------------------------------------------
// Prep A: x (fp32) -> xb (bf16)
// ---------------------------------------------------------------------------
__global__ void conv_x(const float* __restrict__ x,
                       unsigned short* __restrict__ xb, long total) {
    long i0 = (long)(blockIdx.x * blockDim.x + threadIdx.x) * 8;
    long stride = (long)gridDim.x * blockDim.x * 8;
    for (long i = i0; i < total; i += stride) {
        float4 a = *reinterpret_cast<const float4*>(&x[i]);
        float4 b = *reinterpret_cast<const float4*>(&x[i + 4]);
        ushort8 o;
        o[0] = f2bf(a.x); o[1] = f2bf(a.y); o[2] = f2bf(a.z); o[3] = f2bf(a.w);
        o[4] = f2bf(b.x); o[5] = f2bf(b.y); o[6] = f2bf(b.z); o[7] = f2bf(b.w);
        *reinterpret_cast<ushort8*>(&xb[i]) = o;
    }
}

// ---------------------------------------------------------------------------
// Prep B: Wt[n][k] = bf16(Wx[k][n])
// ---------------------------------------------------------------------------
__global__ void conv_wt(const float* __restrict__ W,
                        unsigned short* __restrict__ Wt) {
    int n = blockIdx.x;
    int kc = threadIdx.x;   // 0..63
    ushort8 o;
#pragma unroll
    for (int i = 0; i < 8; ++i)
        o[i] = f2bf(W[(size_t)(kc * 8 + i) * HH + n]);
    *reinterpret_cast<ushort8*>(&Wt[(size_t)n * DD + kc * 8]) = o;
}

// ---------------------------------------------------------------------------
// Kernel 1: MFMA bf16 GEMM (validated round 8: ~70us incl. preps)
// ---------------------------------------------------------------------------
#define GBM 128
#define GBN 128
#define GBK 64
#define LDSW 72

__global__ __launch_bounds__(256, 4) void gemm_bf16(
    const unsigned short* __restrict__ A,
    const unsigned short* __restrict__ Bt,
    const float* __restrict__ bias,
    float* __restrict__ C)
{
    __shared__ unsigned short As[GBM * LDSW];
    __shared__ unsigned short Bs[GBN * LDSW];

    const int tid  = threadIdx.x;
    const int m0   = blockIdx.x * GBM;
    const int n0   = blockIdx.y * GBN;
    const int lane = tid & 63;
    const int wave = tid >> 6;
    const int wm   = wave >> 1;
    const int wn   = wave & 1;

    const int srow = tid >> 3;
    const int sch  = tid & 7;

    f32x4 acc[4][4] = {};

    const int arow = wm * 64 + (lane & 15);
    const int brow = wn * 64 + (lane & 15);
    const int koff = (lane >> 4) * 8;

    for (int kt = 0; kt < DD / GBK; ++kt) {
        const int k0 = kt * GBK;
#pragma unroll
        for (int p = 0; p < 4; ++p) {
            const int row = srow + p * 32;
            *reinterpret_cast<ushort8*>(&As[row * LDSW + sch * 8]) =
                *reinterpret_cast<const ushort8*>(
                    &A[(size_t)(m0 + row) * DD + k0 + sch * 8]);
            *reinterpret_cast<ushort8*>(&Bs[row * LDSW + sch * 8]) =
                *reinterpret_cast<const ushort8*>(
                    &Bt[(size_t)(n0 + row) * DD + k0 + sch * 8]);
        }
        __syncthreads();

#pragma unroll
        for (int kk = 0; kk < GBK; kk += 32) {
            bf16x8 af[4], bf[4];
#pragma unroll
            for (int mt = 0; mt < 4; ++mt)
                af[mt] = *reinterpret_cast<const bf16x8*>(
                    &As[(arow + mt * 16) * LDSW + kk + koff]);
#pragma unroll
            for (int nt = 0; nt < 4; ++nt)
                bf[nt] = *reinterpret_cast<const bf16x8*>(
                    &Bs[(brow + nt * 16) * LDSW + kk + koff]);
#pragma unroll
            for (int mt = 0; mt < 4; ++mt)
#pragma unroll
                for (int nt = 0; nt < 4; ++nt)
                    acc[mt][nt] = __builtin_amdgcn_mfma_f32_16x16x32_bf16(
                        af[mt], bf[nt], acc[mt][nt], 0, 0, 0);
        }
        __syncthreads();
    }

#pragma unroll
    for (int nt = 0; nt < 4; ++nt) {
        const int col = n0 + wn * 64 + nt * 16 + (lane & 15);
        const float bv = bias[col];
#pragma unroll
        for (int mt = 0; mt < 4; ++mt) {
            const int rbase = m0 + wm * 64 + mt * 16 + (lane >> 4) * 4;
#pragma unroll
            for (int r = 0; r < 4; ++r)
                C[(size_t)(rbase + r) * HH + col] = acc[mt][nt][r] + bv;
        }
    }
}

// ---------------------------------------------------------------------------
// Kernel 1 (fallback): fp32 VALU GEMM
// ---------------------------------------------------------------------------
#define BM 128
#define BN 128
#define BK 8

__global__ __launch_bounds__(256, 2) void gemm_xw(
    const float* __restrict__ A,
    const float* __restrict__ B,
    const float* __restrict__ bias,
    float* __restrict__ C)
{
    __shared__ float As[BK][BM];
    __shared__ float Bs[BK][BN];

    const int tid  = threadIdx.x;
    const int tm   = tid >> 4;
    const int tn   = tid & 15;
    const int row0 = blockIdx.x * BM;
    const int col0 = blockIdx.y * BN;

    const int ar = tid >> 1;
    const int ac = (tid & 1) * 4;
    const int br = tid >> 5;
    const int bc = (tid & 31) * 4;

    float acc[8][8];
#pragma unroll
    for (int i = 0; i < 8; ++i)
#pragma unroll
        for (int j = 0; j < 8; ++j) acc[i][j] = 0.f;

    for (int k0 = 0; k0 < DD; k0 += BK) {
        float4 av = *reinterpret_cast<const float4*>(
            &A[(size_t)(row0 + ar) * DD + k0 + ac]);
        float4 bv = *reinterpret_cast<const float4*>(
            &B[(size_t)(k0 + br) * HH + col0 + bc]);

        As[ac + 0][ar] = av.x;
        As[ac + 1][ar] = av.y;
        As[ac + 2][ar] = av.z;
        As[ac + 3][ar] = av.w;
        *reinterpret_cast<float4*>(&Bs[br][bc]) = bv;
        __syncthreads();

#pragma unroll
        for (int kk = 0; kk < BK; ++kk) {
            float a[8], b[8];
            *reinterpret_cast<float4*>(&a[0]) =
                *reinterpret_cast<const float4*>(&As[kk][tm * 8]);
            *reinterpret_cast<float4*>(&a[4]) =
                *reinterpret_cast<const float4*>(&As[kk][tm * 8 + 4]);
            *reinterpret_cast<float4*>(&b[0]) =
                *reinterpret_cast<const float4*>(&Bs[kk][tn * 8]);
            *reinterpret_cast<float4*>(&b[4]) =
                *reinterpret_cast<const float4*>(&Bs[kk][tn * 8 + 4]);
#pragma unroll
            for (int i = 0; i < 8; ++i)
#pragma unroll
                for (int j = 0; j < 8; ++j)
                    acc[i][j] = fmaf(a[i], b[j], acc[i][j]);
        }
        __syncthreads();
    }

#pragma unroll
    for (int i = 0; i < 8; ++i) {
        const int row = row0 + tm * 8 + i;
#pragma unroll
        for (int j = 0; j < 8; j += 4) {
            const int col = col0 + tn * 8 + j;
            float4 o;
            o.x = acc[i][j + 0] + bias[col + 0];
            o.y = acc[i][j + 1] + bias[col + 1];
            o.z = acc[i][j + 2] + bias[col + 2];
            o.w = acc[i][j + 3] + bias[col + 3];
            *reinterpret_cast<float4*>(&C[(size_t)row * HH + col]) = o;
        }
    }
}

// ---------------------------------------------------------------------------
// Kernel 2: grouped scan (round-4 structure) + XCC_ID rendezvous so each
// batch's 4 blocks are GUARANTEED same-XCD -> mirror exchange via shared
// XCD L2 (plain 8B store, sc0 polling, ~200cy) with agent-scope truth
// copy as the every-8th-spin fallback (never deadlocks; wrong-model
// worst case = round-7 speed).
//
// Rendezvous: meta[0..7] per-XCD counters, meta[8] done-counter (zeroed
// by hipMemsetAsync each launch). Each block: xcd = s_getreg(XCC_ID);
// pos = fetch_add(meta[xcd]); barrier (all 256 co-resident: 1024 thr,
// <=128 VGPR, 10KB LDS -> 1 block/CU); read final counts; deterministic
// assignment: full quads per XCD -> fast batches (same-XCD group),
// remainder quads (normally none) -> slow batches (agent path).
//
// Packet protocol per copy unchanged from round 4: 8B {tag,value},
// 2-slot parity, relaxed agent/plain stores, replay-safe.
// ---------------------------------------------------------------------------
__global__ __launch_bounds__(1024, 4) void rnn_scan_xcd(
    const float* __restrict__ Wh,     // (H, H) fp32 row-major
    const float* __restrict__ h0,     // (N, H)
    float* __restrict__ out,          // (N, T, H): in = xw, out = h
    uint64_t* __restrict__ truth,     // [NB][2][HH] agent-scope packets
    uint64_t* __restrict__ mirror,    // [NB][2][HH] XCD-L2 packets
    int* __restrict__ meta)           // [16] rendezvous counters
{
    __shared__ __align__(16) uint32_t hp[2][HH / 2];
    __shared__ float partial[16][128];
    __shared__ int sh_batch, sh_role, sh_fast;

    const int tid = threadIdx.x;

    // ---- rendezvous: physical-XCD-aware group assignment ----
    int xcd_raw;
    asm volatile("s_getreg_b32 %0, hwreg(HW_REG_XCC_ID)" : "=s"(xcd_raw));
    const int xcd = xcd_raw & 7;

    if (tid == 0) {
        int pos = __hip_atomic_fetch_add(&meta[xcd], 1, __ATOMIC_RELAXED,
                                         __HIP_MEMORY_SCOPE_AGENT);
        __hip_atomic_fetch_add(&meta[8], 1, __ATOMIC_RELEASE,
                               __HIP_MEMORY_SCOPE_AGENT);
        while (__hip_atomic_load(&meta[8], __ATOMIC_ACQUIRE,
                                 __HIP_MEMORY_SCOPE_AGENT) < 256)
            __builtin_amdgcn_s_sleep(8);
        int c[8];
#pragma unroll
        for (int q = 0; q < 8; ++q)
            c[q] = __hip_atomic_load(&meta[q], __ATOMIC_RELAXED,
                                     __HIP_MEMORY_SCOPE_AGENT);
        int totalfull = 0, basefull = 0, rembase = 0;
#pragma unroll
        for (int q = 0; q < 8; ++q) totalfull += c[q] >> 2;
        for (int q = 0; q < xcd; ++q) {
            basefull += c[q] >> 2;
            rembase  += c[q] & 3;
        }
        const int nf4 = (c[xcd] >> 2) << 2;
        if (pos < nf4) {             // full same-XCD quad -> fast group
            sh_batch = basefull + (pos >> 2);
            sh_role  = pos & 3;
            sh_fast  = 1;
        } else {                     // remainder -> mixed group, agent path
            int ridx = rembase + (pos - nf4);
            sh_batch = totalfull + (ridx >> 2);
            sh_role  = ridx & 3;
            sh_fast  = 0;
        }
    }
    __syncthreads();

    const int n    = sh_batch;         // batch 0..63
    const int jb   = sh_role << 7;     // column base
    const int fast = sh_fast;

    const int w = tid >> 6;            // wave 0..15 -> k slice [w*32,+32)
    const int l = tid & 63;

    // ---- one-time: weight slice -> registers as packed fp16 ----
    uint32_t w0[16], w1[16];
    {
        const float* wc = Wh + (size_t)(w * 32) * HH + jb + l;
#pragma unroll
        for (int p = 0; p < 16; ++p) {
            float e0 = wc[(size_t)(2 * p) * HH];
            float e1 = wc[(size_t)(2 * p + 1) * HH];
            w0[p] = __builtin_bit_cast(uint32_t, __floats2half2_rn(e0, e1));
            float f0 = wc[(size_t)(2 * p) * HH + 64];
            float f1 = wc[(size_t)(2 * p + 1) * HH + 64];
            w1[p] = __builtin_bit_cast(uint32_t, __floats2half2_rn(f0, f1));
        }
    }

    if (tid < HH)
        ((__half*)hp[0])[tid] = __float2half(h0[(size_t)n * HH + tid]);
    __syncthreads();

    float* outn = out + (size_t)n * TT * HH;
    uint64_t* tru = truth  + (size_t)n * 2 * HH;
    uint64_t* mir = mirror + (size_t)n * 2 * HH;

    const int rcol = (jb + 128 + (tid - 128)) & (HH - 1);

    int cur = 0;
    for (int t = 0; t < TT; ++t) {
        const uint32_t T = (uint32_t)(t + 1);
        const int slot = (int)(T & 1u);

        float xw_r = 0.f;
        if (tid < 128) xw_r = outn[(size_t)t * HH + jb + tid];

        const uint32_t* hpw = &hp[cur][w * 16];
        float a0 = 0.f, a1 = 0.f, b0 = 0.f, b1 = 0.f;
#pragma unroll
        for (int q = 0; q < 4; ++q) {
            uint4 hv = ((const uint4*)hpw)[q];
            a0 = dot2f(hv.x, w0[4 * q + 0], a0);
            b0 = dot2f(hv.x, w1[4 * q + 0], b0);
            a1 = dot2f(hv.y, w0[4 * q + 1], a1);
            b1 = dot2f(hv.y, w1[4 * q + 1], b1);
            a0 = dot2f(hv.z, w0[4 * q + 2], a0);
            b0 = dot2f(hv.z, w1[4 * q + 2], b0);
            a1 = dot2f(hv.w, w0[4 * q + 3], a1);
            b1 = dot2f(hv.w, w1[4 * q + 3], b1);
        }
        partial[w][l] = a0 + a1;
        partial[w][64 + l] = b0 + b1;
        __syncthreads();                                      // B1

        __half* hpn = (__half*)hp[cur ^ 1];
        if (tid < 128) {
            float s = 0.f;
#pragma unroll
            for (int ww = 0; ww < 16; ++ww) s += partial[ww][tid];
            float h = fast_tanh(s + xw_r);
            outn[(size_t)t * HH + jb + tid] = h;
            hpn[jb + tid] = __float2half(h);
            uint64_t pk = ((uint64_t)T << 32) |
                          (uint64_t)__builtin_bit_cast(uint32_t, h);
            const int off = slot * HH + jb + tid;
            if (fast) {   // plain store -> shared-XCD L2 (separate address)
                asm volatile("global_store_dwordx2 %0, %1, off"
                             :: "v"((uint64_t)&mir[off]), "v"(pk) : "memory");
            }
            __hip_atomic_store(&tru[off], pk, __ATOMIC_RELAXED,
                               __HIP_MEMORY_SCOPE_AGENT);
        } else if (tid < 512) {
            const int off = slot * HH + rcol;
            uint64_t v;
            if (fast) {
                uint64_t maddr = (uint64_t)&mir[off];
                int spins = 0;
                while (true) {
                    asm volatile("global_load_dwordx2 %0, %1, off sc0\n\t"
                                 "s_waitcnt vmcnt(0)"
                                 : "=v"(v) : "v"(maddr));
                    if ((uint32_t)(v >> 32) == T) break;
                    if ((++spins & 7) == 0) {
                        v = __hip_atomic_load(&tru[off], __ATOMIC_RELAXED,
                                              __HIP_MEMORY_SCOPE_AGENT);
                        if ((uint32_t)(v >> 32) == T) break;
                    }
                }
            } else {
                v = __hip_atomic_load(&tru[off], __ATOMIC_RELAXED,
                                      __HIP_MEMORY_SCOPE_AGENT);
                while ((uint32_t)(v >> 32) != T) {
                    __builtin_amdgcn_s_sleep(1);
                    v = __hip_atomic_load(&tru[off], __ATOMIC_RELAXED,
                                          __HIP_MEMORY_SCOPE_AGENT);
                }
            }
            hpn[rcol] = __float2half(__builtin_bit_cast(float, (uint32_t)v));
        }
        __syncthreads();                                      // B2
        cur ^= 1;
    }
}

// ---------------------------------------------------------------------------
// Fallback scan (no workspace needed)
// ---------------------------------------------------------------------------
__global__ __launch_bounds__(512, 2) void rnn_scan_f32(
    const float* __restrict__ Wh,
    const float* __restrict__ h0,
    float* __restrict__ out)
{
    __shared__ float hbuf[2][HH];
    const int n = blockIdx.x;
    const int j = threadIdx.x;

    hbuf[0][j] = h0[(size_t)n * HH + j];
    __syncthreads();

    float* outn = out + (size_t)n * TT * HH;
    const float* __restrict__ wp = Wh + j;

    int cur = 0;
    for (int t = 0; t < TT; ++t) {
        float acc = outn[(size_t)t * HH + j];
        const float* hc = hbuf[cur];
#pragma unroll 4
        for (int k = 0; k < HH; k += 4) {
            float4 hv = *reinterpret_cast<const float4*>(&hc[k]);
            acc = fmaf(hv.x, wp[(size_t)(k + 0) * HH], acc);
            acc = fmaf(hv.y, wp[(size_t)(k + 1) * HH], acc);
            acc = fmaf(hv.z, wp[(size_t)(k + 2) * HH], acc);
            acc = fmaf(hv.w, wp[(size_t)(k + 3) * HH], acc);
        }
        float hn = tanhf(acc);
        outn[(size_t)t * HH + j] = hn;
        hbuf[cur ^ 1][j] = hn;
        cur ^= 1;
        __syncthreads();
    }
}

// ---------------------------------------------------------------------------
extern "C" void kernel_launch(void* const* d_in, const int* in_sizes, int n_in,
                              void* d_out, int out_size, void* d_ws, size_t ws_size,
                              hipStream_t stream) {
    const float* x  = (const float*)d_in[0];   // (N, T, D)
    const float* h0 = (const float*)d_in[1];   // (N, H)
    const float* Wx = (const float*)d_in[2];   // (D, H)
    const float* Wh = (const float*)d_in[3];   // (H, H)
    const float* b  = (const float*)d_in[4];   // (H)
    float* out = (float*)d_out;                // (N, T, H)

    const long   M      = (long)NB * TT;                 // 65536
    const size_t pkt_b  = (size_t)NB * 2 * HH * 8;       // 512 KB per region
    const size_t meta_b = 4096;
    const size_t wt_b   = (size_t)HH * DD * 2;           // 512 KB
    const size_t xb_b   = (size_t)M * DD * 2;            // 64 MB

    const size_t off_mir  = pkt_b;
    const size_t off_meta = 2 * pkt_b;
    const size_t off_wt   = 2 * pkt_b + meta_b;
    const size_t off_xb   = off_wt + wt_b;
    const size_t need_all = off_xb + xb_b;
    const size_t need_mid = 2 * pkt_b + meta_b;

    if (ws_size >= need_all) {
        uint64_t*       truth  = (uint64_t*)d_ws;
        uint64_t*       mirror = (uint64_t*)((char*)d_ws + off_mir);
        int*            meta   = (int*)((char*)d_ws + off_meta);
        unsigned short* Wt     = (unsigned short*)((char*)d_ws + off_wt);
        unsigned short* xb     = (unsigned short*)((char*)d_ws + off_xb);

        hipMemsetAsync(meta, 0, 64, stream);   // rendezvous counters
        conv_x<<<2048, 256, 0, stream>>>(x, xb, M * DD);
        conv_wt<<<HH, 64, 0, stream>>>(Wx, Wt);
        dim3 gg(M / GBM, HH / GBN);
        gemm_bf16<<<gg, 256, 0, stream>>>(xb, Wt, b, out);
        rnn_scan_xcd<<<256, 1024, 0, stream>>>(Wh, h0, out, truth, mirror, meta);
    } else if (ws_size >= need_mid) {
        uint64_t* truth  = (uint64_t*)d_ws;
        uint64_t* mirror = (uint64_t*)((char*)d_ws + off_mir);
        int*      meta   = (int*)((char*)d_ws + off_meta);
        hipMemsetAsync(meta, 0, 64, stream);
        dim3 g1(M / BM, HH / BN);
        gemm_xw<<<g1, 256, 0, stream>>>(x, Wx, b, out);
        rnn_scan_xcd<<<256, 1024, 0, stream>>>(Wh, h0, out, truth, mirror, meta);
    } else {
        dim3 g1(M / BM, HH / BN);
        gemm_xw<<<g1, 256, 0, stream>>>(x, Wx, b, out);
        rnn_scan_f32<<<NB, 512, 0, stream>>>(Wh, h0, out);
    }
}

// Round 10
// 1735.575 us; speedup vs baseline: 1.3573x; 1.3573x over previous
//
#include <hip/hip_runtime.h>
#include <hip/hip_fp16.h>
#include <cstddef>
#include <cstdint>

#define NB 64
#define TT 1024
#define DD 512
#define HH 512

typedef _Float16 h2_t __attribute__((ext_vector_type(2)));
typedef __attribute__((ext_vector_type(8))) short bf16x8;
typedef __attribute__((ext_vector_type(4))) float f32x4;
typedef __attribute__((ext_vector_type(8))) unsigned short ushort8;

__device__ __forceinline__ float dot2f(uint32_t a, uint32_t b, float c) {
#if __has_builtin(__builtin_amdgcn_fdot2)
    return __builtin_amdgcn_fdot2(__builtin_bit_cast(h2_t, a),
                                  __builtin_bit_cast(h2_t, b), c, false);
#else
    __half2 av = __builtin_bit_cast(__half2, a);
    __half2 bv = __builtin_bit_cast(__half2, b);
    float2 af = __half22float2(av), bf = __half22float2(bv);
    return fmaf(af.x, bf.x, fmaf(af.y, bf.y, c));
#endif
}

// fast tanh: |err| ~1e-7 (validated r5/r8: absmax unchanged)
__device__ __forceinline__ float fast_tanh(float z) {
    z = fmaxf(-15.f, fminf(15.f, z));
    float u = __builtin_amdgcn_exp2f(-2.885390082f * z);
    return (1.f - u) * __builtin_amdgcn_rcpf(1.f + u);
}

// fp32 -> bf16 bits, round-to-nearest-even
__device__ __forceinline__ unsigned short f2bf(float f) {
    uint32_t u = __builtin_bit_cast(uint32_t, f);
    u += 0x7FFFu + ((u >> 16) & 1u);
    return (unsigned short)(u >> 16);
}

// ---------------------------------------------------------------------------
// Prep A: x (fp32) -> xb (bf16)
// ---------------------------------------------------------------------------
__global__ void conv_x(const float* __restrict__ x,
                       unsigned short* __restrict__ xb, long total) {
    long i0 = (long)(blockIdx.x * blockDim.x + threadIdx.x) * 8;
    long stride = (long)gridDim.x * blockDim.x * 8;
    for (long i = i0; i < total; i += stride) {
        float4 a = *reinterpret_cast<const float4*>(&x[i]);
        float4 b = *reinterpret_cast<const float4*>(&x[i + 4]);
        ushort8 o;
        o[0] = f2bf(a.x); o[1] = f2bf(a.y); o[2] = f2bf(a.z); o[3] = f2bf(a.w);
        o[4] = f2bf(b.x); o[5] = f2bf(b.y); o[6] = f2bf(b.z); o[7] = f2bf(b.w);
        *reinterpret_cast<ushort8*>(&xb[i]) = o;
    }
}

// ---------------------------------------------------------------------------
// Prep B: Wt[n][k] = bf16(Wx[k][n])
// ---------------------------------------------------------------------------
__global__ void conv_wt(const float* __restrict__ W,
                        unsigned short* __restrict__ Wt) {
    int n = blockIdx.x;
    int kc = threadIdx.x;   // 0..63
    ushort8 o;
#pragma unroll
    for (int i = 0; i < 8; ++i)
        o[i] = f2bf(W[(size_t)(kc * 8 + i) * HH + n]);
    *reinterpret_cast<ushort8*>(&Wt[(size_t)n * DD + kc * 8]) = o;
}

// ---------------------------------------------------------------------------
// Kernel 1: MFMA bf16 GEMM (validated round 8: ~70us incl. preps)
// ---------------------------------------------------------------------------
#define GBM 128
#define GBN 128
#define GBK 64
#define LDSW 72

__global__ __launch_bounds__(256, 4) void gemm_bf16(
    const unsigned short* __restrict__ A,
    const unsigned short* __restrict__ Bt,
    const float* __restrict__ bias,
    float* __restrict__ C)
{
    __shared__ unsigned short As[GBM * LDSW];
    __shared__ unsigned short Bs[GBN * LDSW];

    const int tid  = threadIdx.x;
    const int m0   = blockIdx.x * GBM;
    const int n0   = blockIdx.y * GBN;
    const int lane = tid & 63;
    const int wave = tid >> 6;
    const int wm   = wave >> 1;
    const int wn   = wave & 1;

    const int srow = tid >> 3;
    const int sch  = tid & 7;

    f32x4 acc[4][4] = {};

    const int arow = wm * 64 + (lane & 15);
    const int brow = wn * 64 + (lane & 15);
    const int koff = (lane >> 4) * 8;

    for (int kt = 0; kt < DD / GBK; ++kt) {
        const int k0 = kt * GBK;
#pragma unroll
        for (int p = 0; p < 4; ++p) {
            const int row = srow + p * 32;
            *reinterpret_cast<ushort8*>(&As[row * LDSW + sch * 8]) =
                *reinterpret_cast<const ushort8*>(
                    &A[(size_t)(m0 + row) * DD + k0 + sch * 8]);
            *reinterpret_cast<ushort8*>(&Bs[row * LDSW + sch * 8]) =
                *reinterpret_cast<const ushort8*>(
                    &Bt[(size_t)(n0 + row) * DD + k0 + sch * 8]);
        }
        __syncthreads();

#pragma unroll
        for (int kk = 0; kk < GBK; kk += 32) {
            bf16x8 af[4], bf[4];
#pragma unroll
            for (int mt = 0; mt < 4; ++mt)
                af[mt] = *reinterpret_cast<const bf16x8*>(
                    &As[(arow + mt * 16) * LDSW + kk + koff]);
#pragma unroll
            for (int nt = 0; nt < 4; ++nt)
                bf[nt] = *reinterpret_cast<const bf16x8*>(
                    &Bs[(brow + nt * 16) * LDSW + kk + koff]);
#pragma unroll
            for (int mt = 0; mt < 4; ++mt)
#pragma unroll
                for (int nt = 0; nt < 4; ++nt)
                    acc[mt][nt] = __builtin_amdgcn_mfma_f32_16x16x32_bf16(
                        af[mt], bf[nt], acc[mt][nt], 0, 0, 0);
        }
        __syncthreads();
    }

#pragma unroll
    for (int nt = 0; nt < 4; ++nt) {
        const int col = n0 + wn * 64 + nt * 16 + (lane & 15);
        const float bv = bias[col];
#pragma unroll
        for (int mt = 0; mt < 4; ++mt) {
            const int rbase = m0 + wm * 64 + mt * 16 + (lane >> 4) * 4;
#pragma unroll
            for (int r = 0; r < 4; ++r)
                C[(size_t)(rbase + r) * HH + col] = acc[mt][nt][r] + bv;
        }
    }
}

// ---------------------------------------------------------------------------
// Kernel 1 (fallback): fp32 VALU GEMM
// ---------------------------------------------------------------------------
#define BM 128
#define BN 128
#define BK 8

__global__ __launch_bounds__(256, 2) void gemm_xw(
    const float* __restrict__ A,
    const float* __restrict__ B,
    const float* __restrict__ bias,
    float* __restrict__ C)
{
    __shared__ float As[BK][BM];
    __shared__ float Bs[BK][BN];

    const int tid  = threadIdx.x;
    const int tm   = tid >> 4;
    const int tn   = tid & 15;
    const int row0 = blockIdx.x * BM;
    const int col0 = blockIdx.y * BN;

    const int ar = tid >> 1;
    const int ac = (tid & 1) * 4;
    const int br = tid >> 5;
    const int bc = (tid & 31) * 4;

    float acc[8][8];
#pragma unroll
    for (int i = 0; i < 8; ++i)
#pragma unroll
        for (int j = 0; j < 8; ++j) acc[i][j] = 0.f;

    for (int k0 = 0; k0 < DD; k0 += BK) {
        float4 av = *reinterpret_cast<const float4*>(
            &A[(size_t)(row0 + ar) * DD + k0 + ac]);
        float4 bv = *reinterpret_cast<const float4*>(
            &B[(size_t)(k0 + br) * HH + col0 + bc]);

        As[ac + 0][ar] = av.x;
        As[ac + 1][ar] = av.y;
        As[ac + 2][ar] = av.z;
        As[ac + 3][ar] = av.w;
        *reinterpret_cast<float4*>(&Bs[br][bc]) = bv;
        __syncthreads();

#pragma unroll
        for (int kk = 0; kk < BK; ++kk) {
            float a[8], b[8];
            *reinterpret_cast<float4*>(&a[0]) =
                *reinterpret_cast<const float4*>(&As[kk][tm * 8]);
            *reinterpret_cast<float4*>(&a[4]) =
                *reinterpret_cast<const float4*>(&As[kk][tm * 8 + 4]);
            *reinterpret_cast<float4*>(&b[0]) =
                *reinterpret_cast<const float4*>(&Bs[kk][tn * 8]);
            *reinterpret_cast<float4*>(&b[4]) =
                *reinterpret_cast<const float4*>(&Bs[kk][tn * 8 + 4]);
#pragma unroll
            for (int i = 0; i < 8; ++i)
#pragma unroll
                for (int j = 0; j < 8; ++j)
                    acc[i][j] = fmaf(a[i], b[j], acc[i][j]);
        }
        __syncthreads();
    }

#pragma unroll
    for (int i = 0; i < 8; ++i) {
        const int row = row0 + tm * 8 + i;
#pragma unroll
        for (int j = 0; j < 8; j += 4) {
            const int col = col0 + tn * 8 + j;
            float4 o;
            o.x = acc[i][j + 0] + bias[col + 0];
            o.y = acc[i][j + 1] + bias[col + 1];
            o.z = acc[i][j + 2] + bias[col + 2];
            o.w = acc[i][j + 3] + bias[col + 3];
            *reinterpret_cast<float4*>(&C[(size_t)row * HH + col]) = o;
        }
    }
}

// ---------------------------------------------------------------------------
// Kernel 2: DUAL-BATCH grouped scan.
// 128 blocks x 1024 threads. Block b = (g = b&31, r = b>>5) serves batches
// {2g, 2g+1} with role r (columns [r*128, r*128+128)).
// Wave-group s = tid>>9 (waves 0-7 / 8-15) owns batch 2g+s END TO END:
//   local = tid&511; w = local>>6 (k-slice [w*64,+64)); producers local<128;
//   pollers local in [128,512) — one remote packet each, exactly round-4's
//   role split but per group. Both groups share block barriers, so their
//   ~2600cy exposed L3 sync waits OVERLAP -> ~2 steps per round-trip.
// Weights: each thread 64 packed-fp16 VGPRs (statically indexed), its
// group's k-range of the role's 128-col slice.
// Exchange protocol byte-identical to round 4: 8B packet {tag T, fp32 h},
// [NB][2][HH] 2-slot parity, single relaxed agent-scope store, relaxed
// agent-scope poll, no init needed, graph-replay-safe (stale tags
// mismatch or carry bit-identical deterministic values; 0xAA never
// matches a valid tag).
// Residency: 128 blocks, 16 waves, VGPR<=128 (bounds(1024,4)), LDS 12.5KB
// -> all co-resident on 256 CUs; quad {g,32+g,64+g,96+g} is a closed
// system -> spin is deadlock-free.
// ---------------------------------------------------------------------------
__global__ __launch_bounds__(1024, 4) void rnn_scan_dual(
    const float* __restrict__ Wh,    // (H, H) fp32 row-major
    const float* __restrict__ h0,    // (N, H)
    float* __restrict__ out,         // (N, T, H): in = xw, out = h
    uint64_t* __restrict__ exch)     // [NB][2][HH] tagged packets
{
    __shared__ __align__(16) uint32_t hp[2][2][HH / 2]; // [batch][par][pairs]
    __shared__ float partial[2][8][128];

    const int b   = blockIdx.x;      // 0..127
    const int g   = b & 31;          // batch-pair 0..31
    const int r   = b >> 5;          // role 0..3
    const int jb  = r << 7;          // column base

    const int tid   = threadIdx.x;
    const int s     = tid >> 9;      // batch select 0/1
    const int local = tid & 511;
    const int n     = 2 * g + s;     // batch 0..63

    const int w = local >> 6;        // wave-in-group 0..7 -> k [w*64, w*64+64)
    const int l = local & 63;        // lane -> columns jb+l, jb+64+l

    // ---- one-time: weight slice -> 64 packed-fp16 regs ----
    uint32_t w0[32], w1[32];
    {
        const float* wc = Wh + (size_t)(w * 64) * HH + jb + l;
#pragma unroll
        for (int p = 0; p < 32; ++p) {
            float e0 = wc[(size_t)(2 * p) * HH];
            float e1 = wc[(size_t)(2 * p + 1) * HH];
            w0[p] = __builtin_bit_cast(uint32_t, __floats2half2_rn(e0, e1));
            float f0 = wc[(size_t)(2 * p) * HH + 64];
            float f1 = wc[(size_t)(2 * p + 1) * HH + 64];
            w1[p] = __builtin_bit_cast(uint32_t, __floats2half2_rn(f0, f1));
        }
    }

    // init: 1024 threads = 2 batches x 512 cols
    ((__half*)hp[s][0])[local] = __float2half(h0[(size_t)n * HH + local]);
    __syncthreads();

    float* outn = out + (size_t)n * TT * HH;
    uint64_t* ex = exch + (size_t)n * 2 * HH;

    // poller remote column (local in 128..511)
    const int rcol = (jb + 128 + (local - 128)) & (HH - 1);

    int cur = 0;
    for (int t = 0; t < TT; ++t) {
        const uint32_t T = (uint32_t)(t + 1);
        const int slot = (int)(T & 1u);

        // prefetch this step's xw for own columns (consumed after B1)
        float xw_r = 0.f;
        if (local < 128) xw_r = outn[(size_t)t * HH + jb + local];

        // partial dot: k in [w*64, w*64+64) for cols jb+l, jb+64+l
        const uint32_t* hpw = &hp[s][cur][w * 32];
        float a0 = 0.f, a1 = 0.f, b0 = 0.f, b1 = 0.f;
#pragma unroll
        for (int q = 0; q < 8; ++q) {
            uint4 hv = ((const uint4*)hpw)[q];
            a0 = dot2f(hv.x, w0[4 * q + 0], a0);
            b0 = dot2f(hv.x, w1[4 * q + 0], b0);
            a1 = dot2f(hv.y, w0[4 * q + 1], a1);
            b1 = dot2f(hv.y, w1[4 * q + 1], b1);
            a0 = dot2f(hv.z, w0[4 * q + 2], a0);
            b0 = dot2f(hv.z, w1[4 * q + 2], b0);
            a1 = dot2f(hv.w, w0[4 * q + 3], a1);
            b1 = dot2f(hv.w, w1[4 * q + 3], b1);
        }
        partial[s][w][l] = a0 + a1;
        partial[s][w][64 + l] = b0 + b1;
        __syncthreads();                                      // B1

        __half* hpn = (__half*)hp[s][cur ^ 1];
        if (local < 128) {
            // producers: reduce 8 partials + tanh + write + publish
            float sum = 0.f;
#pragma unroll
            for (int ww = 0; ww < 8; ++ww) sum += partial[s][ww][local];
            float h = fast_tanh(sum + xw_r);
            outn[(size_t)t * HH + jb + local] = h;
            hpn[jb + local] = __float2half(h);
            uint64_t pk = ((uint64_t)T << 32) |
                          (uint64_t)__builtin_bit_cast(uint32_t, h);
            __hip_atomic_store(&ex[slot * HH + jb + local], pk,
                               __ATOMIC_RELAXED, __HIP_MEMORY_SCOPE_AGENT);
        } else {
            // pollers: one remote packet each (concurrent across groups)
            uint64_t pk = __hip_atomic_load(&ex[slot * HH + rcol],
                                            __ATOMIC_RELAXED,
                                            __HIP_MEMORY_SCOPE_AGENT);
            while ((uint32_t)(pk >> 32) != T) {
                __builtin_amdgcn_s_sleep(1);
                pk = __hip_atomic_load(&ex[slot * HH + rcol],
                                       __ATOMIC_RELAXED,
                                       __HIP_MEMORY_SCOPE_AGENT);
            }
            hpn[rcol] = __float2half(__builtin_bit_cast(float, (uint32_t)pk));
        }
        __syncthreads();                                      // B2
        cur ^= 1;
    }
}

// ---------------------------------------------------------------------------
// Fallback scan (no workspace needed)
// ---------------------------------------------------------------------------
__global__ __launch_bounds__(512, 2) void rnn_scan_f32(
    const float* __restrict__ Wh,
    const float* __restrict__ h0,
    float* __restrict__ out)
{
    __shared__ float hbuf[2][HH];
    const int n = blockIdx.x;
    const int j = threadIdx.x;

    hbuf[0][j] = h0[(size_t)n * HH + j];
    __syncthreads();

    float* outn = out + (size_t)n * TT * HH;
    const float* __restrict__ wp = Wh + j;

    int cur = 0;
    for (int t = 0; t < TT; ++t) {
        float acc = outn[(size_t)t * HH + j];
        const float* hc = hbuf[cur];
#pragma unroll 4
        for (int k = 0; k < HH; k += 4) {
            float4 hv = *reinterpret_cast<const float4*>(&hc[k]);
            acc = fmaf(hv.x, wp[(size_t)(k + 0) * HH], acc);
            acc = fmaf(hv.y, wp[(size_t)(k + 1) * HH], acc);
            acc = fmaf(hv.z, wp[(size_t)(k + 2) * HH], acc);
            acc = fmaf(hv.w, wp[(size_t)(k + 3) * HH], acc);
        }
        float hn = tanhf(acc);
        outn[(size_t)t * HH + j] = hn;
        hbuf[cur ^ 1][j] = hn;
        cur ^= 1;
        __syncthreads();
    }
}

// ---------------------------------------------------------------------------
extern "C" void kernel_launch(void* const* d_in, const int* in_sizes, int n_in,
                              void* d_out, int out_size, void* d_ws, size_t ws_size,
                              hipStream_t stream) {
    const float* x  = (const float*)d_in[0];   // (N, T, D)
    const float* h0 = (const float*)d_in[1];   // (N, H)
    const float* Wx = (const float*)d_in[2];   // (D, H)
    const float* Wh = (const float*)d_in[3];   // (H, H)
    const float* b  = (const float*)d_in[4];   // (H)
    float* out = (float*)d_out;                // (N, T, H)

    const long   M      = (long)NB * TT;               // 65536
    const size_t exch_b = (size_t)NB * 2 * HH * 8;     // 512 KB
    const size_t wt_b   = (size_t)HH * DD * 2;         // 512 KB
    const size_t xb_b   = (size_t)M * DD * 2;          // 64 MB
    const size_t need_all = exch_b + wt_b + xb_b;
    const size_t need_mid = exch_b;

    if (ws_size >= need_all) {
        uint64_t*       exch = (uint64_t*)d_ws;
        unsigned short* Wt   = (unsigned short*)((char*)d_ws + exch_b);
        unsigned short* xb   = (unsigned short*)((char*)d_ws + exch_b + wt_b);

        conv_x<<<2048, 256, 0, stream>>>(x, xb, M * DD);
        conv_wt<<<HH, 64, 0, stream>>>(Wx, Wt);
        dim3 gg(M / GBM, HH / GBN);
        gemm_bf16<<<gg, 256, 0, stream>>>(xb, Wt, b, out);
        rnn_scan_dual<<<128, 1024, 0, stream>>>(Wh, h0, out, exch);
    } else if (ws_size >= need_mid) {
        dim3 g1(M / BM, HH / BN);
        gemm_xw<<<g1, 256, 0, stream>>>(x, Wx, b, out);
        rnn_scan_dual<<<128, 1024, 0, stream>>>(Wh, h0, out, (uint64_t*)d_ws);
    } else {
        dim3 g1(M / BM, HH / BN);
        gemm_xw<<<g1, 256, 0, stream>>>(x, Wx, b, out);
        rnn_scan_f32<<<NB, 512, 0, stream>>>(Wh, h0, out);
    }
}

// Round 11
// 1370.018 us; speedup vs baseline: 1.7194x; 1.2668x over previous
//
#include <hip/hip_runtime.h>
#include <hip/hip_fp16.h>
#include <cstddef>
#include <cstdint>

#define NB 64
#define TT 1024
#define DD 512
#define HH 512

typedef _Float16 h2_t __attribute__((ext_vector_type(2)));
typedef __attribute__((ext_vector_type(8))) short bf16x8;
typedef __attribute__((ext_vector_type(4))) float f32x4;
typedef __attribute__((ext_vector_type(8))) unsigned short ushort8;

__device__ __forceinline__ float dot2f(uint32_t a, uint32_t b, float c) {
#if __has_builtin(__builtin_amdgcn_fdot2)
    return __builtin_amdgcn_fdot2(__builtin_bit_cast(h2_t, a),
                                  __builtin_bit_cast(h2_t, b), c, false);
#else
    __half2 av = __builtin_bit_cast(__half2, a);
    __half2 bv = __builtin_bit_cast(__half2, b);
    float2 af = __half22float2(av), bf = __half22float2(bv);
    return fmaf(af.x, bf.x, fmaf(af.y, bf.y, c));
#endif
}

// fast tanh: |err| ~1e-7 (validated r5/r8: absmax unchanged)
__device__ __forceinline__ float fast_tanh(float z) {
    z = fmaxf(-15.f, fminf(15.f, z));
    float u = __builtin_amdgcn_exp2f(-2.885390082f * z);
    return (1.f - u) * __builtin_amdgcn_rcpf(1.f + u);
}

// fp32 -> bf16 bits, round-to-nearest-even
__device__ __forceinline__ unsigned short f2bf(float f) {
    uint32_t u = __builtin_bit_cast(uint32_t, f);
    u += 0x7FFFu + ((u >> 16) & 1u);
    return (unsigned short)(u >> 16);
}

// ---------------------------------------------------------------------------
// Prep A: x (fp32) -> xb (bf16)
// ---------------------------------------------------------------------------
__global__ void conv_x(const float* __restrict__ x,
                       unsigned short* __restrict__ xb, long total) {
    long i0 = (long)(blockIdx.x * blockDim.x + threadIdx.x) * 8;
    long stride = (long)gridDim.x * blockDim.x * 8;
    for (long i = i0; i < total; i += stride) {
        float4 a = *reinterpret_cast<const float4*>(&x[i]);
        float4 b = *reinterpret_cast<const float4*>(&x[i + 4]);
        ushort8 o;
        o[0] = f2bf(a.x); o[1] = f2bf(a.y); o[2] = f2bf(a.z); o[3] = f2bf(a.w);
        o[4] = f2bf(b.x); o[5] = f2bf(b.y); o[6] = f2bf(b.z); o[7] = f2bf(b.w);
        *reinterpret_cast<ushort8*>(&xb[i]) = o;
    }
}

// ---------------------------------------------------------------------------
// Prep B: Wt[n][k] = bf16(Wx[k][n])
// ---------------------------------------------------------------------------
__global__ void conv_wt(const float* __restrict__ W,
                        unsigned short* __restrict__ Wt) {
    int n = blockIdx.x;
    int kc = threadIdx.x;   // 0..63
    ushort8 o;
#pragma unroll
    for (int i = 0; i < 8; ++i)
        o[i] = f2bf(W[(size_t)(kc * 8 + i) * HH + n]);
    *reinterpret_cast<ushort8*>(&Wt[(size_t)n * DD + kc * 8]) = o;
}

// ---------------------------------------------------------------------------
// Kernel 1: MFMA bf16 GEMM (validated round 8: ~70us incl. preps)
// ---------------------------------------------------------------------------
#define GBM 128
#define GBN 128
#define GBK 64
#define LDSW 72

__global__ __launch_bounds__(256, 4) void gemm_bf16(
    const unsigned short* __restrict__ A,
    const unsigned short* __restrict__ Bt,
    const float* __restrict__ bias,
    float* __restrict__ C)
{
    __shared__ unsigned short As[GBM * LDSW];
    __shared__ unsigned short Bs[GBN * LDSW];

    const int tid  = threadIdx.x;
    const int m0   = blockIdx.x * GBM;
    const int n0   = blockIdx.y * GBN;
    const int lane = tid & 63;
    const int wave = tid >> 6;
    const int wm   = wave >> 1;
    const int wn   = wave & 1;

    const int srow = tid >> 3;
    const int sch  = tid & 7;

    f32x4 acc[4][4] = {};

    const int arow = wm * 64 + (lane & 15);
    const int brow = wn * 64 + (lane & 15);
    const int koff = (lane >> 4) * 8;

    for (int kt = 0; kt < DD / GBK; ++kt) {
        const int k0 = kt * GBK;
#pragma unroll
        for (int p = 0; p < 4; ++p) {
            const int row = srow + p * 32;
            *reinterpret_cast<ushort8*>(&As[row * LDSW + sch * 8]) =
                *reinterpret_cast<const ushort8*>(
                    &A[(size_t)(m0 + row) * DD + k0 + sch * 8]);
            *reinterpret_cast<ushort8*>(&Bs[row * LDSW + sch * 8]) =
                *reinterpret_cast<const ushort8*>(
                    &Bt[(size_t)(n0 + row) * DD + k0 + sch * 8]);
        }
        __syncthreads();

#pragma unroll
        for (int kk = 0; kk < GBK; kk += 32) {
            bf16x8 af[4], bf[4];
#pragma unroll
            for (int mt = 0; mt < 4; ++mt)
                af[mt] = *reinterpret_cast<const bf16x8*>(
                    &As[(arow + mt * 16) * LDSW + kk + koff]);
#pragma unroll
            for (int nt = 0; nt < 4; ++nt)
                bf[nt] = *reinterpret_cast<const bf16x8*>(
                    &Bs[(brow + nt * 16) * LDSW + kk + koff]);
#pragma unroll
            for (int mt = 0; mt < 4; ++mt)
#pragma unroll
                for (int nt = 0; nt < 4; ++nt)
                    acc[mt][nt] = __builtin_amdgcn_mfma_f32_16x16x32_bf16(
                        af[mt], bf[nt], acc[mt][nt], 0, 0, 0);
        }
        __syncthreads();
    }

#pragma unroll
    for (int nt = 0; nt < 4; ++nt) {
        const int col = n0 + wn * 64 + nt * 16 + (lane & 15);
        const float bv = bias[col];
#pragma unroll
        for (int mt = 0; mt < 4; ++mt) {
            const int rbase = m0 + wm * 64 + mt * 16 + (lane >> 4) * 4;
#pragma unroll
            for (int r = 0; r < 4; ++r)
                C[(size_t)(rbase + r) * HH + col] = acc[mt][nt][r] + bv;
        }
    }
}

// ---------------------------------------------------------------------------
// Kernel 1 (fallback): fp32 VALU GEMM
// ---------------------------------------------------------------------------
#define BM 128
#define BN 128
#define BK 8

__global__ __launch_bounds__(256, 2) void gemm_xw(
    const float* __restrict__ A,
    const float* __restrict__ B,
    const float* __restrict__ bias,
    float* __restrict__ C)
{
    __shared__ float As[BK][BM];
    __shared__ float Bs[BK][BN];

    const int tid  = threadIdx.x;
    const int tm   = tid >> 4;
    const int tn   = tid & 15;
    const int row0 = blockIdx.x * BM;
    const int col0 = blockIdx.y * BN;

    const int ar = tid >> 1;
    const int ac = (tid & 1) * 4;
    const int br = tid >> 5;
    const int bc = (tid & 31) * 4;

    float acc[8][8];
#pragma unroll
    for (int i = 0; i < 8; ++i)
#pragma unroll
        for (int j = 0; j < 8; ++j) acc[i][j] = 0.f;

    for (int k0 = 0; k0 < DD; k0 += BK) {
        float4 av = *reinterpret_cast<const float4*>(
            &A[(size_t)(row0 + ar) * DD + k0 + ac]);
        float4 bv = *reinterpret_cast<const float4*>(
            &B[(size_t)(k0 + br) * HH + col0 + bc]);

        As[ac + 0][ar] = av.x;
        As[ac + 1][ar] = av.y;
        As[ac + 2][ar] = av.z;
        As[ac + 3][ar] = av.w;
        *reinterpret_cast<float4*>(&Bs[br][bc]) = bv;
        __syncthreads();

#pragma unroll
        for (int kk = 0; kk < BK; ++kk) {
            float a[8], b[8];
            *reinterpret_cast<float4*>(&a[0]) =
                *reinterpret_cast<const float4*>(&As[kk][tm * 8]);
            *reinterpret_cast<float4*>(&a[4]) =
                *reinterpret_cast<const float4*>(&As[kk][tm * 8 + 4]);
            *reinterpret_cast<float4*>(&b[0]) =
                *reinterpret_cast<const float4*>(&Bs[kk][tn * 8]);
            *reinterpret_cast<float4*>(&b[4]) =
                *reinterpret_cast<const float4*>(&Bs[kk][tn * 8 + 4]);
#pragma unroll
            for (int i = 0; i < 8; ++i)
#pragma unroll
                for (int j = 0; j < 8; ++j)
                    acc[i][j] = fmaf(a[i], b[j], acc[i][j]);
        }
        __syncthreads();
    }

#pragma unroll
    for (int i = 0; i < 8; ++i) {
        const int row = row0 + tm * 8 + i;
#pragma unroll
        for (int j = 0; j < 8; j += 4) {
            const int col = col0 + tn * 8 + j;
            float4 o;
            o.x = acc[i][j + 0] + bias[col + 0];
            o.y = acc[i][j + 1] + bias[col + 1];
            o.z = acc[i][j + 2] + bias[col + 2];
            o.w = acc[i][j + 3] + bias[col + 3];
            *reinterpret_cast<float4*>(&C[(size_t)row * HH + col]) = o;
        }
    }
}

// ---------------------------------------------------------------------------
// Kernel 2: grouped scan (r4/r8 structure) + XCC_ID rendezvous + L2-ATOMIC
// mirror fast path.
//
// Mechanism (final test of intra-XCD family): atomic RMWs are executed at
// the L2 atomic units and can never be served from L1. Producer publishes
// the mirror packet with global_atomic_swap_x2 (no sc1 -> XCD scope, lands
// at the shared L2); consumer polls with a RETURNING global_atomic_add_x2
// of 0 (sc0 = return-old) at the same L2 unit. Inline asm because LLVM
// canonicalizes idempotent fetch_add(0) into an atomic LOAD (re-entering
// the L1 problem that killed r9's sc0-load polling).
// Dual-poll EVERY iteration (mirror then truth) so the failure mode costs
// ~100-200cy/step, not r9's every-8th gating (+60%).
// Truth copy (relaxed agent-scope) is unchanged from r4: always correct
// under any placement; tag/parity/replay safety as established.
//
// Residency: 256 blocks x 16 waves, VGPR<=128, LDS ~11KB -> all
// co-resident; quads are closed systems -> spin is deadlock-free.
// ---------------------------------------------------------------------------
__global__ __launch_bounds__(1024, 4) void rnn_scan_l2a(
    const float* __restrict__ Wh,     // (H, H) fp32 row-major
    const float* __restrict__ h0,     // (N, H)
    float* __restrict__ out,          // (N, T, H): in = xw, out = h
    uint64_t* __restrict__ truth,     // [NB][2][HH] agent-scope packets
    uint64_t* __restrict__ mirror,    // [NB][2][HH] XCD-L2 packets
    int* __restrict__ meta)           // [16] rendezvous counters (pre-zeroed)
{
    __shared__ __align__(16) uint32_t hp[2][HH / 2];
    __shared__ float partial[16][128];
    __shared__ int sh_batch, sh_role, sh_fast;

    const int tid = threadIdx.x;

    // ---- rendezvous: physical-XCD-aware group assignment (r9, proven) ----
    int xcd_raw;
    asm volatile("s_getreg_b32 %0, hwreg(HW_REG_XCC_ID)" : "=s"(xcd_raw));
    const int xcd = xcd_raw & 7;

    if (tid == 0) {
        int pos = __hip_atomic_fetch_add(&meta[xcd], 1, __ATOMIC_RELAXED,
                                         __HIP_MEMORY_SCOPE_AGENT);
        __hip_atomic_fetch_add(&meta[8], 1, __ATOMIC_RELEASE,
                               __HIP_MEMORY_SCOPE_AGENT);
        while (__hip_atomic_load(&meta[8], __ATOMIC_ACQUIRE,
                                 __HIP_MEMORY_SCOPE_AGENT) < 256)
            __builtin_amdgcn_s_sleep(8);
        int c[8];
#pragma unroll
        for (int q = 0; q < 8; ++q)
            c[q] = __hip_atomic_load(&meta[q], __ATOMIC_RELAXED,
                                     __HIP_MEMORY_SCOPE_AGENT);
        int totalfull = 0, basefull = 0, rembase = 0;
#pragma unroll
        for (int q = 0; q < 8; ++q) totalfull += c[q] >> 2;
        for (int q = 0; q < xcd; ++q) {
            basefull += c[q] >> 2;
            rembase  += c[q] & 3;
        }
        const int nf4 = (c[xcd] >> 2) << 2;
        if (pos < nf4) {             // full same-XCD quad -> fast group
            sh_batch = basefull + (pos >> 2);
            sh_role  = pos & 3;
            sh_fast  = 1;
        } else {                     // remainder -> mixed group, agent path
            int ridx = rembase + (pos - nf4);
            sh_batch = totalfull + (ridx >> 2);
            sh_role  = ridx & 3;
            sh_fast  = 0;
        }
    }
    __syncthreads();

    const int n    = sh_batch;
    const int jb   = sh_role << 7;
    const int fast = sh_fast;

    const int w = tid >> 6;            // wave 0..15 -> k slice [w*32,+32)
    const int l = tid & 63;

    // ---- one-time: weight slice -> registers as packed fp16 ----
    uint32_t w0[16], w1[16];
    {
        const float* wc = Wh + (size_t)(w * 32) * HH + jb + l;
#pragma unroll
        for (int p = 0; p < 16; ++p) {
            float e0 = wc[(size_t)(2 * p) * HH];
            float e1 = wc[(size_t)(2 * p + 1) * HH];
            w0[p] = __builtin_bit_cast(uint32_t, __floats2half2_rn(e0, e1));
            float f0 = wc[(size_t)(2 * p) * HH + 64];
            float f1 = wc[(size_t)(2 * p + 1) * HH + 64];
            w1[p] = __builtin_bit_cast(uint32_t, __floats2half2_rn(f0, f1));
        }
    }

    if (tid < HH)
        ((__half*)hp[0])[tid] = __float2half(h0[(size_t)n * HH + tid]);
    __syncthreads();

    float* outn = out + (size_t)n * TT * HH;
    uint64_t* tru = truth  + (size_t)n * 2 * HH;
    uint64_t* mir = mirror + (size_t)n * 2 * HH;

    const int rcol = (jb + 128 + (tid - 128)) & (HH - 1);

    int cur = 0;
    for (int t = 0; t < TT; ++t) {
        const uint32_t T = (uint32_t)(t + 1);
        const int slot = (int)(T & 1u);

        float xw_r = 0.f;
        if (tid < 128) xw_r = outn[(size_t)t * HH + jb + tid];

        const uint32_t* hpw = &hp[cur][w * 16];
        float a0 = 0.f, a1 = 0.f, b0 = 0.f, b1 = 0.f;
#pragma unroll
        for (int q = 0; q < 4; ++q) {
            uint4 hv = ((const uint4*)hpw)[q];
            a0 = dot2f(hv.x, w0[4 * q + 0], a0);
            b0 = dot2f(hv.x, w1[4 * q + 0], b0);
            a1 = dot2f(hv.y, w0[4 * q + 1], a1);
            b1 = dot2f(hv.y, w1[4 * q + 1], b1);
            a0 = dot2f(hv.z, w0[4 * q + 2], a0);
            b0 = dot2f(hv.z, w1[4 * q + 2], b0);
            a1 = dot2f(hv.w, w0[4 * q + 3], a1);
            b1 = dot2f(hv.w, w1[4 * q + 3], b1);
        }
        partial[w][l] = a0 + a1;
        partial[w][64 + l] = b0 + b1;
        __syncthreads();                                      // B1

        __half* hpn = (__half*)hp[cur ^ 1];
        if (tid < 128) {
            float s = 0.f;
#pragma unroll
            for (int ww = 0; ww < 16; ++ww) s += partial[ww][tid];
            float h = fast_tanh(s + xw_r);
            uint64_t pk = ((uint64_t)T << 32) |
                          (uint64_t)__builtin_bit_cast(uint32_t, h);
            const int off = slot * HH + jb + tid;
            // publish FIRST (critical path), side-writes after
            if (fast) {   // atomic swap, no sc1 -> executes at this XCD's L2
                asm volatile("global_atomic_swap_x2 %0, %1, off"
                             :: "v"((uint64_t)&mir[off]), "v"(pk) : "memory");
            }
            __hip_atomic_store(&tru[off], pk, __ATOMIC_RELAXED,
                               __HIP_MEMORY_SCOPE_AGENT);
            outn[(size_t)t * HH + jb + tid] = h;
            hpn[jb + tid] = __float2half(h);
        } else if (tid < 512) {
            const int off = slot * HH + rcol;
            uint64_t v;
            if (fast) {
                const uint64_t maddr = (uint64_t)&mir[off];
                const uint64_t zero = 0;
                while (true) {
                    // returning atomic add(0): RMW at the shared L2 unit,
                    // sc0 = return old value. Never served from L1.
                    asm volatile(
                        "global_atomic_add_x2 %0, %1, %2, off sc0\n\t"
                        "s_waitcnt vmcnt(0)"
                        : "=v"(v) : "v"(maddr), "v"(zero) : "memory");
                    if ((uint32_t)(v >> 32) == T) break;
                    v = __hip_atomic_load(&tru[off], __ATOMIC_RELAXED,
                                          __HIP_MEMORY_SCOPE_AGENT);
                    if ((uint32_t)(v >> 32) == T) break;
                }
            } else {
                v = __hip_atomic_load(&tru[off], __ATOMIC_RELAXED,
                                      __HIP_MEMORY_SCOPE_AGENT);
                while ((uint32_t)(v >> 32) != T) {
                    __builtin_amdgcn_s_sleep(1);
                    v = __hip_atomic_load(&tru[off], __ATOMIC_RELAXED,
                                          __HIP_MEMORY_SCOPE_AGENT);
                }
            }
            hpn[rcol] = __float2half(__builtin_bit_cast(float, (uint32_t)v));
        }
        __syncthreads();                                      // B2
        cur ^= 1;
    }
}

// ---------------------------------------------------------------------------
// Fallback scan (no workspace needed)
// ---------------------------------------------------------------------------
__global__ __launch_bounds__(512, 2) void rnn_scan_f32(
    const float* __restrict__ Wh,
    const float* __restrict__ h0,
    float* __restrict__ out)
{
    __shared__ float hbuf[2][HH];
    const int n = blockIdx.x;
    const int j = threadIdx.x;

    hbuf[0][j] = h0[(size_t)n * HH + j];
    __syncthreads();

    float* outn = out + (size_t)n * TT * HH;
    const float* __restrict__ wp = Wh + j;

    int cur = 0;
    for (int t = 0; t < TT; ++t) {
        float acc = outn[(size_t)t * HH + j];
        const float* hc = hbuf[cur];
#pragma unroll 4
        for (int k = 0; k < HH; k += 4) {
            float4 hv = *reinterpret_cast<const float4*>(&hc[k]);
            acc = fmaf(hv.x, wp[(size_t)(k + 0) * HH], acc);
            acc = fmaf(hv.y, wp[(size_t)(k + 1) * HH], acc);
            acc = fmaf(hv.z, wp[(size_t)(k + 2) * HH], acc);
            acc = fmaf(hv.w, wp[(size_t)(k + 3) * HH], acc);
        }
        float hn = tanhf(acc);
        outn[(size_t)t * HH + j] = hn;
        hbuf[cur ^ 1][j] = hn;
        cur ^= 1;
        __syncthreads();
    }
}

// ---------------------------------------------------------------------------
extern "C" void kernel_launch(void* const* d_in, const int* in_sizes, int n_in,
                              void* d_out, int out_size, void* d_ws, size_t ws_size,
                              hipStream_t stream) {
    const float* x  = (const float*)d_in[0];   // (N, T, D)
    const float* h0 = (const float*)d_in[1];   // (N, H)
    const float* Wx = (const float*)d_in[2];   // (D, H)
    const float* Wh = (const float*)d_in[3];   // (H, H)
    const float* b  = (const float*)d_in[4];   // (H)
    float* out = (float*)d_out;                // (N, T, H)

    const long   M      = (long)NB * TT;                 // 65536
    const size_t pkt_b  = (size_t)NB * 2 * HH * 8;       // 512 KB per region
    const size_t meta_b = 4096;
    const size_t wt_b   = (size_t)HH * DD * 2;           // 512 KB
    const size_t xb_b   = (size_t)M * DD * 2;            // 64 MB

    const size_t off_mir  = pkt_b;
    const size_t off_meta = 2 * pkt_b;
    const size_t off_wt   = 2 * pkt_b + meta_b;
    const size_t off_xb   = off_wt + wt_b;
    const size_t need_all = off_xb + xb_b;
    const size_t need_mid = 2 * pkt_b + meta_b;

    if (ws_size >= need_all) {
        uint64_t*       truth  = (uint64_t*)d_ws;
        uint64_t*       mirror = (uint64_t*)((char*)d_ws + off_mir);
        int*            meta   = (int*)((char*)d_ws + off_meta);
        unsigned short* Wt     = (unsigned short*)((char*)d_ws + off_wt);
        unsigned short* xb     = (unsigned short*)((char*)d_ws + off_xb);

        conv_x<<<2048, 256, 0, stream>>>(x, xb, M * DD);
        conv_wt<<<HH, 64, 0, stream>>>(Wx, Wt);
        dim3 gg(M / GBM, HH / GBN);
        gemm_bf16<<<gg, 256, 0, stream>>>(xb, Wt, b, out);
        hipMemsetAsync(meta, 0, 64, stream);   // rendezvous counters
        rnn_scan_l2a<<<256, 1024, 0, stream>>>(Wh, h0, out, truth, mirror, meta);
    } else if (ws_size >= need_mid) {
        uint64_t* truth  = (uint64_t*)d_ws;
        uint64_t* mirror = (uint64_t*)((char*)d_ws + off_mir);
        int*      meta   = (int*)((char*)d_ws + off_meta);
        dim3 g1(M / BM, HH / BN);
        gemm_xw<<<g1, 256, 0, stream>>>(x, Wx, b, out);
        hipMemsetAsync(meta, 0, 64, stream);
        rnn_scan_l2a<<<256, 1024, 0, stream>>>(Wh, h0, out, truth, mirror, meta);
    } else {
        dim3 g1(M / BM, HH / BN);
        gemm_xw<<<g1, 256, 0, stream>>>(x, Wx, b, out);
        rnn_scan_f32<<<NB, 512, 0, stream>>>(Wh, h0, out);
    }
}